// Round 4
// baseline (192.190 us; speedup 1.0000x reference)
//
#include <hip/hip_runtime.h>

// DeltaSynapse: I[b,o] = sum_{d,e} s_e*W[e,o]*delaymap[d,e,o]*Xd[d,b,e]*(1+Wshort[d,b,e])
// Xd is ~2% sparse. v5: fused scan+accumulate as in v4, but the o-range is
// split 4-way so the grid is 2048 small blocks (~8/CU) instead of 512 huge
// ones (2/CU). Per-block work ~ Poisson(10) entry count; with blocks queued
// behind resident ones the scheduler rebalances and the slowest-block tail
// (~2.4x mean at 2 blocks/CU, all-resident) disappears.

constexpr int D = 8, B = 16, E = 2048, O = 2048;
constexpr int DB = D * B;
constexpr int ESPLIT = 4;             // e-range chunks (and slice split)
constexpr int ECHUNK = E / ESPLIT;    // 512 e's per chunk
constexpr int NSLICE = D * ESPLIT;    // 32 partial slices
constexpr int OSPLIT = 4;             // o-range tiles per (part, db)
constexpr int OTILE = O / OSPLIT;     // 512 o-columns per block
constexpr int THREADS2 = OTILE / 4;   // 128 threads, float4 per thread

struct Entry { int e; float c; };

// ---------------- Pass A: fused scan+compact+accumulate ----------------
__global__ __launch_bounds__(THREADS2) void accum_fused(
    const float* __restrict__ W, const float* __restrict__ dm,
    const float* __restrict__ Xd, const float* __restrict__ Wshort,
    const int* __restrict__ signs, float* __restrict__ partial)
{
    const int tile = blockIdx.x;            // 0 .. OSPLIT-1
    const int part = blockIdx.y;            // 0 .. ESPLIT-1
    const int db   = blockIdx.z;            // 0 .. DB-1
    const int d = db >> 4;                  // db / B
    const int b = db & 15;                  // db % B
    const int e0 = part * ECHUNK;

    __shared__ int cnt;
    __shared__ Entry sh[ECHUNK];            // 4 KB
    if (threadIdx.x == 0) cnt = 0;
    __syncthreads();

    // Scan this (db, chunk): 128 float4s, one per thread.
    {
        const int q = threadIdx.x;
        float4 x = ((const float4*)(Xd + (size_t)db * E + e0))[q];
        if (x.x != 0.f || x.y != 0.f || x.z != 0.f || x.w != 0.f) {
            float4 ws = ((const float4*)(Wshort + (size_t)db * E + e0))[q];
            int4   sg = ((const int4*)(signs + e0))[q];
            const float xa[4] = {x.x, x.y, x.z, x.w};
            const float wa[4] = {ws.x, ws.y, ws.z, ws.w};
            const int   sa[4] = {sg.x, sg.y, sg.z, sg.w};
            #pragma unroll
            for (int k = 0; k < 4; ++k) {
                if (xa[k] != 0.f) {
                    float s = (float)(2 * sa[k] - 1);     // {0,1} -> {-1,+1}
                    float c = xa[k] * s * (1.0f + wa[k]);
                    int slot = atomicAdd(&cnt, 1);        // LDS atomic, order irrelevant
                    sh[slot].e = e0 + q * 4 + k;
                    sh[slot].c = c;
                }
            }
        }
    }
    __syncthreads();
    const int m = cnt;

    const int o0 = tile * OTILE + (int)threadIdx.x * 4;
    const float* __restrict__ Wt  = W  + o0;
    const float* __restrict__ dmd = dm + (size_t)d * E * O + o0;
    float4 acc = make_float4(0.f, 0.f, 0.f, 0.f);
    #pragma unroll 4
    for (int j = 0; j < m; ++j) {
        Entry en = sh[j];                   // uniform address -> LDS broadcast
        const float4 w  = *(const float4*)(Wt  + (size_t)en.e * O);
        const float4 mm = *(const float4*)(dmd + (size_t)en.e * O);
        acc.x += en.c * w.x * mm.x;
        acc.y += en.c * w.y * mm.y;
        acc.z += en.c * w.z * mm.z;
        acc.w += en.c * w.w * mm.w;
    }

    // Unconditional full-coverage write -> no pre-zeroing needed.
    float* p = partial + ((size_t)(d * ESPLIT + part) * B + b) * O + o0;
    *(float4*)p = acc;
}

// ---------------- Pass B: reduce 32 slices -> I ----------------
__global__ __launch_bounds__(128) void reduce_slices(
    const float* __restrict__ partial, float* __restrict__ Iout)
{
    const int q = blockIdx.x * 128 + threadIdx.x;   // float2 index, 0 .. B*O/2-1
    const float2* __restrict__ p = (const float2*)partial;
    float2 s = make_float2(0.f, 0.f);
    #pragma unroll
    for (int k = 0; k < NSLICE; ++k) {
        float2 v = p[(size_t)k * (B * O / 2) + q];
        s.x += v.x; s.y += v.y;
    }
    ((float2*)Iout)[q] = s;
}

extern "C" void kernel_launch(void* const* d_in, const int* in_sizes, int n_in,
                              void* d_out, int out_size, void* d_ws, size_t ws_size,
                              hipStream_t stream) {
    const float* W     = (const float*)d_in[0];   // (E, O)
    const float* Xd    = (const float*)d_in[1];   // (D, B, E)
    const float* dm    = (const float*)d_in[2];   // (D, E, O)
    const float* Wsh   = (const float*)d_in[3];   // (D, B, E)
    const int*   signs = (const int*)d_in[4];     // (E,)
    float* Iout = (float*)d_out;                  // (B, O) fp32

    // workspace layout: [0, 4MB) partial[NSLICE][B][O]
    float* partial = (float*)d_ws;

    accum_fused<<<dim3(OSPLIT, ESPLIT, DB), dim3(THREADS2), 0, stream>>>(
        W, dm, Xd, Wsh, signs, partial);
    reduce_slices<<<dim3(B * O / (128 * 2)), dim3(128), 0, stream>>>(partial, Iout);
}